// Round 10
// baseline (1092.533 us; speedup 1.0000x reference)
//
#include <hip/hip_runtime.h>
#include <math.h>

#define NN 4096
#define BB 4
#define KK 20
#define OUTC 256
#define GN (BB*NN)

// ---------------- xx[b][n] = sum_c x[b][c][n]^2 ----------------
template<int C>
__global__ void __launch_bounds__(256) xx_kernel(const float* __restrict__ x, int bstride,
                                                 float* __restrict__ xxo) {
  int i = blockIdx.x*256 + threadIdx.x;
  int b = i >> 12, n = i & (NN-1);
  const float* xp = x + (size_t)b*bstride + n;
  float s = 0.f;
#pragma unroll
  for (int c = 0; c < C; ++c) { float v = xp[(size_t)c*NN]; s = fmaf(v, v, s); }
  xxo[i] = s;
}

__device__ __forceinline__ unsigned ord_u32(float v) {
  unsigned b = __float_as_uint(v);
  return (b & 0x80000000u) ? ~b : (b | 0x80000000u);
}

// Exact top-KK extraction from 64 lanes x S register slots via ballot bit-bisect.
// Order semantics: (value desc, idx asc) == jax.lax.top_k. Emits the index SET
// (downstream sum/max over k is order-invariant). Returns true iff this query
// needs the exact-cleanup pass: some lane discarded a value od that could have
// belonged to the true top-20 (ord(od) >= T, conservative on exact ties).
template<int S>
__device__ __forceinline__ bool extract_top20(const float (&sv)[S], const int (&si)[S],
                                              float od, int* __restrict__ outp,
                                              unsigned long long lmask) {
  unsigned u[S];
#pragma unroll
  for (int k = 0; k < S; ++k) u[k] = ord_u32(sv[k]);
  unsigned T = 0u;
#pragma unroll 1
  for (int bit = 31; bit >= 0; --bit) {
    unsigned Tp = T | (1u << bit);
    int c = 0;
#pragma unroll
    for (int k = 0; k < S; ++k) c += __popcll(__ballot(u[k] >= Tp));
    if (c >= KK) T = Tp;
  }
  int cgt = 0;
#pragma unroll
  for (int k = 0; k < S; ++k) cgt += __popcll(__ballot(u[k] > T));
  const int r = KK - cgt;
  int A = 0;
#pragma unroll 1
  for (int bit = 11; bit >= 0; --bit) {
    int Ap = A | (1 << bit);
    int c = 0;
#pragma unroll
    for (int k = 0; k < S; ++k) c += __popcll(__ballot(u[k] == T && si[k] < Ap));
    if (c < r) A = Ap;
  }
  int base = 0;
#pragma unroll
  for (int k = 0; k < S; ++k) {
    bool kp = (u[k] > T) || (u[k] == T && si[k] <= A);
    unsigned long long mk = __ballot(kp);
    int pos = base + __popcll(mk & lmask);
    if (kp) outp[pos] = si[k];
    base += __popcll(mk);
  }
  return __ballot(ord_u32(od) >= T) != 0ull;
}

// ---------------- KNN: double-buffered pipeline, 8 q/wave, top-4/lane + od-flag ------
// R9 lesson: six knn variants all landed at 260-280us because staging latency was
// serialized with compute (stage->barrier->compute). This version double-buffers:
// per phase, ISSUE global loads for phase p+1 into registers, compute phase p from
// LDS buf[p&1], barrier, WRITE regs->buf[(p+1)&1], barrier. HBM/L2 latency hides
// under the ~1200-cyc FMA block. CC=8 channel chunks -> cand[2][8][512] = 32 KB.
// xm read straight from global at distance time (L2-hot, once per tile).
// od invariant (proven R8): od = max over all discards = max(min(d, old sv[S-1])).
// Distance fma chain order identical to the validated R1..R8 kernels.
template<int C>
__global__ void __launch_bounds__(256)
__attribute__((amdgpu_waves_per_eu(2, 2)))
knn8_kernel(const float* __restrict__ x, int bstride,
            const float* __restrict__ xxb,
            int* __restrict__ idx_out,
            int* __restrict__ flag_cnt,
            int* __restrict__ flag_list) {
  constexpr int CC = (C < 8) ? C : 8;
  constexpr int NCH = C / CC;              // 1 for C=3, 8 for C=64
  constexpr int NT = NN/512;               // 8 candidate tiles
  constexpr int P = NT * NCH;              // pipeline phases
  constexpr int NL = (CC*128 + 255)/256;   // float4 stage-loads per thread per phase
  constexpr int S = 4;
  __shared__ float cand[2][CC][512];
  __shared__ float xq_lds[32];
  const int tid = threadIdx.x;
  const int wq = tid >> 6, lane = tid & 63;
  const unsigned long long lmask = (1ull << lane) - 1ull;
  const int qb = blockIdx.x;
  const int b = qb >> 7, n0 = (qb & 127) << 5;
  const float* xb  = x + (size_t)b*bstride;
  const float* xxr = xxb + b*NN;
  const int uwq = __builtin_amdgcn_readfirstlane(wq);
  const float* qp = xb + n0 + uwq*8;

  if (tid < 32) xq_lds[tid] = xxr[n0 + tid];
  __syncthreads();
  float xq[8];
#pragma unroll
  for (int i = 0; i < 8; ++i) xq[i] = xq_lds[wq*8 + i];

  float sv[8][S]; int si[8][S]; float od[8];
#pragma unroll
  for (int i = 0; i < 8; ++i) {
    od[i] = -INFINITY;
#pragma unroll
    for (int k = 0; k < S; ++k) { sv[i][k] = -INFINITY; si[i][k] = 0x7fffffff; }
  }

  float acc[8][8];

  // ---- prologue: stage phase 0 ----
  {
    float4 r0[NL];
#pragma unroll
    for (int l = 0; l < NL; ++l) {
      int idx = tid + l*256;
      if (idx < CC*128) {
        int c = idx >> 7, mc = (idx & 127)*4;
        r0[l] = *reinterpret_cast<const float4*>(&xb[(size_t)c*NN + mc]);
      }
    }
#pragma unroll
    for (int l = 0; l < NL; ++l) {
      int idx = tid + l*256;
      if (idx < CC*128) {
        int c = idx >> 7, mc = (idx & 127)*4;
        *reinterpret_cast<float4*>(&cand[0][c][mc]) = r0[l];
      }
    }
  }
  __syncthreads();

#pragma unroll 1
  for (int p = 0; p < P; ++p) {
    const int tp = p / NCH, cp = p - tp*NCH;
    const int buf = p & 1;
    const int mt0 = tp*512;
    const int cbase = cp*CC;

    // ---- ISSUE loads for phase p+1 (latency hides under compute below) ----
    float4 rB[NL];
    const int pn = p + 1;
    if (pn < P) {
      const int tpn = pn / NCH, cpn = pn - tpn*NCH;
      const int mt0n = tpn*512, cbn = cpn*CC;
#pragma unroll
      for (int l = 0; l < NL; ++l) {
        int idx = tid + l*256;
        if (idx < CC*128) {
          int c = idx >> 7, mc = (idx & 127)*4;
          rB[l] = *reinterpret_cast<const float4*>(&xb[(size_t)(cbn + c)*NN + mt0n + mc]);
        }
      }
    }

    // ---- compute phase p ----
    if (cp == 0) {
#pragma unroll
      for (int i = 0; i < 8; ++i)
#pragma unroll
        for (int j = 0; j < 8; ++j) acc[i][j] = 0.f;
    }
#pragma unroll
    for (int c = 0; c < CC; ++c) {
      const float* qcp = qp + (size_t)(cbase + c)*NN;   // uniform address -> s_load
      float qq[8];
#pragma unroll
      for (int i = 0; i < 8; ++i) qq[i] = qcp[i];
      float4 ca = *reinterpret_cast<const float4*>(&cand[buf][c][lane*4]);
      float4 cb = *reinterpret_cast<const float4*>(&cand[buf][c][256 + lane*4]);
      float mm[8] = {ca.x, ca.y, ca.z, ca.w, cb.x, cb.y, cb.z, cb.w};
#pragma unroll
      for (int i = 0; i < 8; ++i)
#pragma unroll
        for (int j = 0; j < 8; ++j) acc[i][j] = fmaf(qq[i], mm[j], acc[i][j]);
    }

    if (cp == NCH - 1) {
      // distances + selection for tile tp (xm straight from global, L2-hot)
      float4 xma = *reinterpret_cast<const float4*>(&xxr[mt0 + lane*4]);
      float4 xmb = *reinterpret_cast<const float4*>(&xxr[mt0 + 256 + lane*4]);
      float xmv[8] = {xma.x, xma.y, xma.z, xma.w, xmb.x, xmb.y, xmb.z, xmb.w};
#pragma unroll
      for (int i = 0; i < 8; ++i) {
#pragma unroll
        for (int j = 0; j < 8; ++j) {
          const float d = 2.f*acc[i][j] - xq[i] - xmv[j];
          const int mi = mt0 + ((j < 4) ? (lane*4 + j) : (256 + lane*4 + (j - 4)));
          od[i] = fmaxf(od[i], fminf(d, sv[i][3]));     // all discards tracked
          bool c0 = d > sv[i][0], c1 = d > sv[i][1], c2 = d > sv[i][2], c3 = d > sv[i][3];
          sv[i][3] = c2 ? sv[i][2] : (c3 ? d : sv[i][3]);  si[i][3] = c2 ? si[i][2] : (c3 ? mi : si[i][3]);
          sv[i][2] = c1 ? sv[i][1] : (c2 ? d : sv[i][2]);  si[i][2] = c1 ? si[i][1] : (c2 ? mi : si[i][2]);
          sv[i][1] = c0 ? sv[i][0] : (c1 ? d : sv[i][1]);  si[i][1] = c0 ? si[i][0] : (c1 ? mi : si[i][1]);
          sv[i][0] = c0 ? d : sv[i][0];                    si[i][0] = c0 ? mi : si[i][0];
        }
      }
    }

    __syncthreads();
    // ---- WRITE staged regs -> other buffer ----
    if (pn < P) {
#pragma unroll
      for (int l = 0; l < NL; ++l) {
        int idx = tid + l*256;
        if (idx < CC*128) {
          int c = idx >> 7, mc = (idx & 127)*4;
          *reinterpret_cast<float4*>(&cand[buf ^ 1][c][mc]) = rB[l];
        }
      }
    }
    __syncthreads();
  }

  // extraction: fully unrolled over the 8 queries (static register indexing)
#pragma unroll
  for (int i = 0; i < 8; ++i) {
    const int q = n0 + wq*8 + i;
    int* outp = idx_out + (size_t)(b*NN + q)*KK;
    bool need_fix = extract_top20<S>(sv[i], si[i], od[i], outp, lmask);
    if (need_fix) {
      if (lane == 0) { int p = atomicAdd(flag_cnt, 1); flag_list[p & 4095] = b*NN + q; }
    }
  }
}

// ---------------- exact cleanup for flagged queries (rare; ~1 block per query) ------
template<int C>
__global__ void __launch_bounds__(256) knn_fix_kernel(const float* __restrict__ x, int bstride,
                                                      const float* __restrict__ xxb,
                                                      const int* __restrict__ flag_cnt,
                                                      const int* __restrict__ flag_list,
                                                      int* __restrict__ idx_out) {
  __shared__ float redv[4]; __shared__ int redi[4];
  const int tid = threadIdx.x;
  const int wid = tid >> 6, lane = tid & 63;
  const int cnt = flag_cnt[0] < 4096 ? flag_cnt[0] : 4096;
  for (int f = blockIdx.x; f < cnt; f += gridDim.x) {
    const int qn = flag_list[f];
    const int b = qn >> 12, n = qn & (NN-1);
    const float* xb  = x + (size_t)b*bstride;
    const float* xxr = xxb + b*NN;
    float acc[16];
#pragma unroll
    for (int jj = 0; jj < 16; ++jj) acc[jj] = 0.f;
    for (int c = 0; c < C; ++c) {
      const float qc = xb[(size_t)c*NN + n];
      const float* row = xb + (size_t)c*NN + tid;
#pragma unroll
      for (int jj = 0; jj < 16; ++jj) acc[jj] = fmaf(qc, row[256*jj], acc[jj]);
    }
    const float xq = xxr[n];
    float dv[16]; int di[16]; unsigned used = 0;
#pragma unroll
    for (int jj = 0; jj < 16; ++jj) {
      dv[jj] = 2.f*acc[jj] - xq - xxr[tid + 256*jj];
      di[jj] = tid + 256*jj;
    }
    for (int r = 0; r < KK; ++r) {
      float bv = -INFINITY; int bi = 0x7fffffff;
#pragma unroll
      for (int jj = 0; jj < 16; ++jj) {
        bool ok = !((used >> jj) & 1);
        bool bet = ok && (dv[jj] > bv || (dv[jj] == bv && di[jj] < bi));
        bv = bet ? dv[jj] : bv; bi = bet ? di[jj] : bi;
      }
#pragma unroll
      for (int s = 1; s < 64; s <<= 1) {
        float ov = __shfl_xor(bv, s, 64);
        int   oi = __shfl_xor(bi, s, 64);
        if (ov > bv || (ov == bv && oi < bi)) { bv = ov; bi = oi; }
      }
      if (lane == 0) { redv[wid] = bv; redi[wid] = bi; }
      __syncthreads();
#pragma unroll
      for (int w = 0; w < 4; ++w) {
        float ov = redv[w]; int oi = redi[w];
        if (ov > bv || (ov == bv && oi < bi)) { bv = ov; bi = oi; }
      }
      __syncthreads();
      if ((bi & 255) == tid) used |= 1u << (bi >> 8);
      if (tid == 0) idx_out[(size_t)qn*KK + r] = bi;
    }
  }
}

// ---------------- P = W1 . x,  Q = (W2-W1) . x   (both [b][n][o]) ----------------
template<int C, int O>
__global__ void __launch_bounds__(256) pq_kernel(const float* __restrict__ x, int bstride,
                                                 const float* __restrict__ W,
                                                 float* __restrict__ P, float* __restrict__ Q) {
  constexpr int CC = (C < 32) ? C : 32;
  constexpr int NPP = 256 / O;
  constexpr int NITER = 64 / NPP;
  __shared__ float xt[C*64];
  __shared__ float w1t[CC*O];
  __shared__ float wdt[CC*O];
  const int tid = threadIdx.x;
  const int g0 = blockIdx.x*64;
  const int b = g0 >> 12, n0 = g0 & (NN-1);
  for (int i = tid; i < C*64; i += 256) {
    int c = i >> 6, j = i & 63;
    xt[i] = x[(size_t)b*bstride + (size_t)c*NN + (n0 + j)];
  }
  const int o = tid % O;
  const int ns = tid / O;
  float ap[NITER], aq[NITER];
#pragma unroll
  for (int i = 0; i < NITER; ++i) { ap[i] = 0.f; aq[i] = 0.f; }
  for (int cc = 0; cc < C; cc += CC) {
    __syncthreads();
    for (int i = tid; i < CC*O; i += 256) {
      int oo = i % O, c = i / O;
      float w1 = W[oo*(2*C) + cc + c];
      float w2 = W[oo*(2*C) + C + cc + c];
      w1t[c*O + oo] = w1;
      wdt[c*O + oo] = w2 - w1;
    }
    __syncthreads();
#pragma unroll
    for (int np = 0; np < NITER; ++np) {
      const int nl = np*NPP + ns;
#pragma unroll
      for (int c = 0; c < CC; ++c) {
        float xv = xt[(cc + c)*64 + nl];
        ap[np] = fmaf(xv, w1t[c*O + o], ap[np]);
        aq[np] = fmaf(xv, wdt[c*O + o], aq[np]);
      }
    }
  }
#pragma unroll
  for (int np = 0; np < NITER; ++np) {
    const int nl = np*NPP + ns;
    size_t row = (size_t)(g0 + nl)*O + o;
    P[row] = ap[np];
    Q[row] = aq[np];
  }
}

// ---------------- y = P[m]+Q[n]: per-(b,n,o) max/min over k + per-channel partial sums ----
template<int O>
__global__ void __launch_bounds__(256) stats_kernel(const float* __restrict__ P,
                                                    const float* __restrict__ Q,
                                                    const int* __restrict__ idxb,
                                                    float* __restrict__ ymax,
                                                    float* __restrict__ ymin,
                                                    float* __restrict__ parts) {
  constexpr int NPB = 256 / O;
  __shared__ float ls[256], ls2[256];
  const int tid = threadIdx.x;
  const int o = tid % O, ns = tid / O;
  const int g = blockIdx.x*NPB + ns;
  const int b = g >> 12;
  const float qvv = Q[(size_t)g*O + o];
  const int* ip = idxb + (size_t)g*KK;
  const float* Pb = P + (size_t)b*NN*O;
  float s = 0.f, s2 = 0.f, mx = -INFINITY, mn = INFINITY;
#pragma unroll 4
  for (int k = 0; k < KK; ++k) {
    int m = ip[k];
    float yv = Pb[(size_t)m*O + o] + qvv;
    s += yv; s2 = fmaf(yv, yv, s2);
    mx = fmaxf(mx, yv); mn = fminf(mn, yv);
  }
  ymax[(size_t)g*O + o] = mx;
  ymin[(size_t)g*O + o] = mn;
  ls[tid] = s; ls2[tid] = s2;
  __syncthreads();
  if (ns == 0) {
#pragma unroll
    for (int j = 1; j < NPB; ++j) { s += ls[j*O + o]; s2 += ls2[j*O + o]; }
    parts[(size_t)blockIdx.x*2*O + o] = s;
    parts[(size_t)blockIdx.x*2*O + O + o] = s2;
  }
}

// ---------------- per-channel BN affine coefficients (deterministic f64 tree) ----------
template<int O>
__global__ void __launch_bounds__(256) reduce_kernel(const float* __restrict__ parts, int nblocks,
                                                     const float* __restrict__ gg,
                                                     const float* __restrict__ bbp,
                                                     float* __restrict__ chan) {
  __shared__ double sh[512];
  const int o = blockIdx.x, t = threadIdx.x;
  double S = 0.0, S2 = 0.0;
  for (int i = t; i < nblocks; i += 256) {
    S  += (double)parts[(size_t)i*2*O + o];
    S2 += (double)parts[(size_t)i*2*O + O + o];
  }
  sh[t] = S; sh[256+t] = S2;
  __syncthreads();
  for (int s = 128; s > 0; s >>= 1) {
    if (t < s) { sh[t] += sh[t+s]; sh[256+t] += sh[256+t+s]; }
    __syncthreads();
  }
  if (t == 0) {
    const double M = (double)BB*NN*KK;
    double mean = sh[0]/M;
    double var  = sh[256]/M - mean*mean;
    double inv  = 1.0/sqrt(var + 1e-5);
    double A  = (double)gg[o]*inv;
    double Bc = (double)bbp[o] - mean*A;
    chan[2*o]   = (float)A;
    chan[2*o+1] = (float)Bc;
  }
}

// ---------------- out[b][cbase+o][n] = leaky(A*(A>0?ymax:ymin)+Bc), LDS transpose ------
template<int O>
__global__ void __launch_bounds__(256) final_kernel(const float* __restrict__ ymax,
                                                    const float* __restrict__ ymin,
                                                    const float* __restrict__ chan,
                                                    float* __restrict__ out, int cbase) {
  __shared__ float buf[64*(O+1)];
  const int tid = threadIdx.x;
  const int g0 = blockIdx.x*64;
  const int b = g0 >> 12, n0 = g0 & (NN-1);
  for (int i = tid; i < 64*O; i += 256) {
    int o = i % O, nl = i / O;
    size_t r = (size_t)(g0 + nl)*O + o;
    float A = chan[2*o], Bc = chan[2*o+1];
    float v = (A > 0.f) ? ymax[r] : ymin[r];
    float y = fmaf(A, v, Bc);
    buf[nl*(O+1) + o] = (y > 0.f) ? y : 0.2f*y;
  }
  __syncthreads();
  for (int i = tid; i < 64*O; i += 256) {
    int nl = i & 63, o = i >> 6;
    out[(size_t)b*(OUTC*NN) + (size_t)(cbase + o)*NN + (n0 + nl)] = buf[nl*(O+1) + o];
  }
}

extern "C" void kernel_launch(void* const* d_in, const int* in_sizes, int n_in,
                              void* d_out, int out_size, void* d_ws, size_t ws_size,
                              hipStream_t stream) {
  (void)in_sizes; (void)n_in; (void)out_size; (void)ws_size;
  const float* x  = (const float*)d_in[0];
  const float* W0 = (const float*)d_in[1];
  const float* g0 = (const float*)d_in[2];
  const float* b0 = (const float*)d_in[3];
  const float* W1 = (const float*)d_in[4];
  const float* g1 = (const float*)d_in[5];
  const float* b1 = (const float*)d_in[6];
  const float* W2 = (const float*)d_in[7];
  const float* g2 = (const float*)d_in[8];
  const float* b2 = (const float*)d_in[9];
  float* out = (float*)d_out;
  char* ws = (char*)d_ws;

  float* xxb  = (float*)(ws);                       // 64 KB
  int*   idxb = (int*)  (ws + ((size_t)1<<20));     // 1.31 MB
  float* P    = (float*)(ws + ((size_t)4<<20));     // 8 MB
  float* Q    = (float*)(ws + ((size_t)12<<20));    // 8 MB
  float* ymax = (float*)(ws + ((size_t)20<<20));    // 8 MB
  float* ymin = (float*)(ws + ((size_t)28<<20));    // 8 MB
  float* prts = (float*)(ws + ((size_t)36<<20));    // 8 MB
  float* chan = (float*)(ws + ((size_t)44<<20));    // 1 KB
  int*   fcnt = (int*)  (ws + ((size_t)45<<20));    // 3 ints
  int*   flst = (int*)  (ws + ((size_t)45<<20) + 64); // 3*4096 ints

  hipMemsetAsync(fcnt, 0, 3*sizeof(int), stream);

  // ---- layer 0: C=3 -> O=64, out channels [0,64) ----
  xx_kernel<3><<<GN/256, 256, 0, stream>>>(x, 3*NN, xxb);
  knn8_kernel<3><<<GN/32, 256, 0, stream>>>(x, 3*NN, xxb, idxb, fcnt+0, flst+0*4096);
  knn_fix_kernel<3><<<64, 256, 0, stream>>>(x, 3*NN, xxb, fcnt+0, flst+0*4096, idxb);
  pq_kernel<3,64><<<GN/64, 256, 0, stream>>>(x, 3*NN, W0, P, Q);
  stats_kernel<64><<<GN/4, 256, 0, stream>>>(P, Q, idxb, ymax, ymin, prts);
  reduce_kernel<64><<<64, 256, 0, stream>>>(prts, GN/4, g0, b0, chan);
  final_kernel<64><<<GN/64, 256, 0, stream>>>(ymax, ymin, chan, out, 0);

  // ---- layer 1: C=64 -> O=64, input = out[:,0:64,:], out channels [64,128) ----
  const float* x1 = out;
  xx_kernel<64><<<GN/256, 256, 0, stream>>>(x1, OUTC*NN, xxb);
  knn8_kernel<64><<<GN/32, 256, 0, stream>>>(x1, OUTC*NN, xxb, idxb, fcnt+1, flst+1*4096);
  knn_fix_kernel<64><<<64, 256, 0, stream>>>(x1, OUTC*NN, xxb, fcnt+1, flst+1*4096, idxb);
  pq_kernel<64,64><<<GN/64, 256, 0, stream>>>(x1, OUTC*NN, W1, P, Q);
  stats_kernel<64><<<GN/4, 256, 0, stream>>>(P, Q, idxb, ymax, ymin, prts);
  reduce_kernel<64><<<64, 256, 0, stream>>>(prts, GN/4, g1, b1, chan);
  final_kernel<64><<<GN/64, 256, 0, stream>>>(ymax, ymin, chan, out, 64);

  // ---- layer 2: C=64 -> O=128, input = out[:,64:128,:], out channels [128,256) ----
  const float* x2 = out + (size_t)64*NN;
  xx_kernel<64><<<GN/256, 256, 0, stream>>>(x2, OUTC*NN, xxb);
  knn8_kernel<64><<<GN/32, 256, 0, stream>>>(x2, OUTC*NN, xxb, idxb, fcnt+2, flst+2*4096);
  knn_fix_kernel<64><<<64, 256, 0, stream>>>(x2, OUTC*NN, xxb, fcnt+2, flst+2*4096, idxb);
  pq_kernel<64,128><<<GN/64, 256, 0, stream>>>(x2, OUTC*NN, W2, P, Q);
  stats_kernel<128><<<GN/2, 256, 0, stream>>>(P, Q, idxb, ymax, ymin, prts);
  reduce_kernel<128><<<128, 256, 0, stream>>>(prts, GN/2, g2, b2, chan);
  final_kernel<128><<<GN/64, 256, 0, stream>>>(ymax, ymin, chan, out, 128);
}

// Round 11
// 876.970 us; speedup vs baseline: 1.2458x; 1.2458x over previous
//
#include <hip/hip_runtime.h>
#include <math.h>

#define NN 4096
#define BB 4
#define KK 20
#define OUTC 256
#define GN (BB*NN)

typedef unsigned int u32;

// async 16B/lane global -> LDS DMA (wave-uniform LDS base, per-lane global src)
__device__ __forceinline__ void gload_lds16(const float* g, float* l) {
  __builtin_amdgcn_global_load_lds((const __attribute__((address_space(1))) u32*)g,
                                   (__attribute__((address_space(3))) u32*)l, 16, 0, 0);
}

// ---------------- xx[b][n] = sum_c x[b][c][n]^2 ----------------
template<int C>
__global__ void __launch_bounds__(256) xx_kernel(const float* __restrict__ x, int bstride,
                                                 float* __restrict__ xxo) {
  int i = blockIdx.x*256 + threadIdx.x;
  int b = i >> 12, n = i & (NN-1);
  const float* xp = x + (size_t)b*bstride + n;
  float s = 0.f;
#pragma unroll
  for (int c = 0; c < C; ++c) { float v = xp[(size_t)c*NN]; s = fmaf(v, v, s); }
  xxo[i] = s;
}

// ---------------- qt[g][c][j] = x[b][c][g*8+j]: contiguous per-wave q blocks --------
template<int C>
__global__ void __launch_bounds__(256) qt_kernel(const float* __restrict__ x, int bstride,
                                                 float* __restrict__ qt) {
  int o = blockIdx.x*256 + threadIdx.x;          // o < GN*C
  int g = o / (C*8); int r = o - g*(C*8); int c = r >> 3; int j = r & 7;
  int gq = g*8 + j; int b = gq >> 12; int n = gq & (NN-1);
  qt[o] = x[(size_t)b*bstride + (size_t)c*NN + n];
}

__device__ __forceinline__ unsigned ord_u32(float v) {
  unsigned b = __float_as_uint(v);
  return (b & 0x80000000u) ? ~b : (b | 0x80000000u);
}

// Exact top-KK extraction from 64 lanes x S register slots via ballot bit-bisect.
// Order semantics: (value desc, idx asc) == jax.lax.top_k. Emits the index SET
// (downstream sum/max over k is order-invariant). Returns true iff this query
// needs the exact-cleanup pass: some lane discarded a value od that could have
// belonged to the true top-20 (ord(od) >= T, conservative on exact ties).
template<int S>
__device__ __forceinline__ bool extract_top20(const float (&sv)[S], const int (&si)[S],
                                              float od, int* __restrict__ outp,
                                              unsigned long long lmask) {
  unsigned u[S];
#pragma unroll
  for (int k = 0; k < S; ++k) u[k] = ord_u32(sv[k]);
  unsigned T = 0u;
#pragma unroll 1
  for (int bit = 31; bit >= 0; --bit) {
    unsigned Tp = T | (1u << bit);
    int c = 0;
#pragma unroll
    for (int k = 0; k < S; ++k) c += __popcll(__ballot(u[k] >= Tp));
    if (c >= KK) T = Tp;
  }
  int cgt = 0;
#pragma unroll
  for (int k = 0; k < S; ++k) cgt += __popcll(__ballot(u[k] > T));
  const int r = KK - cgt;
  int A = 0;
#pragma unroll 1
  for (int bit = 11; bit >= 0; --bit) {
    int Ap = A | (1 << bit);
    int c = 0;
#pragma unroll
    for (int k = 0; k < S; ++k) c += __popcll(__ballot(u[k] == T && si[k] < Ap));
    if (c < r) A = Ap;
  }
  int base = 0;
#pragma unroll
  for (int k = 0; k < S; ++k) {
    bool kp = (u[k] > T) || (u[k] == T && si[k] <= A);
    unsigned long long mk = __ballot(kp);
    int pos = base + __popcll(mk & lmask);
    if (kp) outp[pos] = si[k];
    base += __popcll(mk);
  }
  return __ballot(ord_u32(od) >= T) != 0ull;
}

// ---------------- KNN: global_load_lds 2-phase pipeline, 8 q/wave, top-4 + od ------
// R10 lesson: register double-buffering spills; the zero-VGPR staging path is
// global_load_lds (compiler never auto-emits it). Per phase: ISSUE async DMA for
// phase p+1 into cand[buf^1], compute phase p from cand[buf], one __syncthreads()
// (its vmcnt(0)+barrier drain completes the DMA for all waves). CC=8 channel
// chunks -> cand[2][8][512] = 32 KB. q values come from the transposed qt array:
// per c one contiguous 32B wave-uniform block -> s_load, no 16KB-stride sL1 thrash.
// od invariant (proven R8): od = max over all discards = max(min(d, old sv[S-1])).
// Distance fma chain order identical to the validated R1..R8 kernels
// (c ascending within each tile).
template<int C>
__global__ void __launch_bounds__(256)
__attribute__((amdgpu_waves_per_eu(2, 2)))
knn9_kernel(const float* __restrict__ x, int bstride,
            const float* __restrict__ xxb,
            const float* __restrict__ qt,
            int* __restrict__ idx_out,
            int* __restrict__ flag_cnt,
            int* __restrict__ flag_list) {
  constexpr int CC = (C < 8) ? C : 8;
  constexpr int NCH = C / CC;              // 1 for C=3, 8 for C=64
  constexpr int NT = NN/512;               // 8 candidate tiles
  constexpr int P = NT * NCH;              // pipeline phases
  constexpr int NSEG = CC*2;               // 1KB DMA segments per chunk
  constexpr int NPW = (NSEG + 3)/4;        // segments per wave
  constexpr int S = 4;
  __shared__ float cand[2][CC][512];
  __shared__ float xq_lds[32];
  const int tid = threadIdx.x;
  const int wq = tid >> 6, lane = tid & 63;
  const unsigned long long lmask = (1ull << lane) - 1ull;
  const int qb = blockIdx.x;
  const int b = qb >> 7, n0 = (qb & 127) << 5;
  const float* xb  = x + (size_t)b*bstride;
  const float* xxr = xxb + b*NN;
  // wave-uniform transposed-q pointer (readfirstlane -> SGPR -> s_load)
  const int ug = __builtin_amdgcn_readfirstlane(((b << 12) + n0 + wq*8) >> 3);
  const float* qtp = qt + (size_t)ug*C*8;

  if (tid < 32) xq_lds[tid] = xxr[n0 + tid];

  // ---- prologue: stage phase 0 into cand[0] ----
#pragma unroll
  for (int i = 0; i < NPW; ++i) {
    int seg = wq*NPW + i;                  // wave-uniform
    if (NSEG == 4*NPW || seg < NSEG) {
      int c = seg >> 1, half = (seg & 1) << 8;
      gload_lds16(xb + (size_t)c*NN + half + lane*4, &cand[0][c][half]);
    }
  }
  __syncthreads();                         // drains DMA + xq_lds writes

  float xq[8];
#pragma unroll
  for (int i = 0; i < 8; ++i) xq[i] = xq_lds[wq*8 + i];

  float sv[8][S]; int si[8][S]; float od[8];
#pragma unroll
  for (int i = 0; i < 8; ++i) {
    od[i] = -INFINITY;
#pragma unroll
    for (int k = 0; k < S; ++k) { sv[i][k] = -INFINITY; si[i][k] = 0x7fffffff; }
  }

  float acc[8][8];

#pragma unroll 1
  for (int p = 0; p < P; ++p) {
    const int tp = p / NCH, cp = p - tp*NCH;
    const int buf = p & 1;
    const int mt0 = tp*512;
    const int cbase = cp*CC;

    // ---- ISSUE async DMA for phase p+1 (zero VGPR cost; lands by next barrier) ----
    const int pn = p + 1;
    if (pn < P) {
      const int tpn = pn / NCH, cpn = pn - tpn*NCH;
      const int mt0n = tpn*512, cbn = cpn*CC;
#pragma unroll
      for (int i = 0; i < NPW; ++i) {
        int seg = wq*NPW + i;
        if (NSEG == 4*NPW || seg < NSEG) {
          int c = seg >> 1, half = (seg & 1) << 8;
          gload_lds16(xb + (size_t)(cbn + c)*NN + mt0n + half + lane*4,
                      &cand[buf ^ 1][c][half]);
        }
      }
    }

    // ---- compute phase p ----
    if (cp == 0) {
#pragma unroll
      for (int i = 0; i < 8; ++i)
#pragma unroll
        for (int j = 0; j < 8; ++j) acc[i][j] = 0.f;
    }
#pragma unroll
    for (int c = 0; c < CC; ++c) {
      const float* qc = qtp + (size_t)(cbase + c)*8;   // uniform 32B -> s_load
      float qq[8];
#pragma unroll
      for (int i = 0; i < 8; ++i) qq[i] = qc[i];
      float4 ca = *reinterpret_cast<const float4*>(&cand[buf][c][lane*4]);
      float4 cb = *reinterpret_cast<const float4*>(&cand[buf][c][256 + lane*4]);
      float mm[8] = {ca.x, ca.y, ca.z, ca.w, cb.x, cb.y, cb.z, cb.w};
#pragma unroll
      for (int i = 0; i < 8; ++i)
#pragma unroll
        for (int j = 0; j < 8; ++j) acc[i][j] = fmaf(qq[i], mm[j], acc[i][j]);
    }

    if (cp == NCH - 1) {
      // distances + selection for tile tp (xm straight from global, L2-hot)
      float4 xma = *reinterpret_cast<const float4*>(&xxr[mt0 + lane*4]);
      float4 xmb = *reinterpret_cast<const float4*>(&xxr[mt0 + 256 + lane*4]);
      float xmv[8] = {xma.x, xma.y, xma.z, xma.w, xmb.x, xmb.y, xmb.z, xmb.w};
#pragma unroll
      for (int i = 0; i < 8; ++i) {
#pragma unroll
        for (int j = 0; j < 8; ++j) {
          const float d = 2.f*acc[i][j] - xq[i] - xmv[j];
          const int mi = mt0 + ((j < 4) ? (lane*4 + j) : (256 + lane*4 + (j - 4)));
          od[i] = fmaxf(od[i], fminf(d, sv[i][3]));     // all discards tracked
          bool c0 = d > sv[i][0], c1 = d > sv[i][1], c2 = d > sv[i][2], c3 = d > sv[i][3];
          sv[i][3] = c2 ? sv[i][2] : (c3 ? d : sv[i][3]);  si[i][3] = c2 ? si[i][2] : (c3 ? mi : si[i][3]);
          sv[i][2] = c1 ? sv[i][1] : (c2 ? d : sv[i][2]);  si[i][2] = c1 ? si[i][1] : (c2 ? mi : si[i][2]);
          sv[i][1] = c0 ? sv[i][0] : (c1 ? d : sv[i][1]);  si[i][1] = c0 ? si[i][0] : (c1 ? mi : si[i][1]);
          sv[i][0] = c0 ? d : sv[i][0];                    si[i][0] = c0 ? mi : si[i][0];
        }
      }
    }

    __syncthreads();   // drains phase p+1 DMA for every wave; guards buffer reuse
  }

  // extraction: fully unrolled over the 8 queries (static register indexing)
#pragma unroll
  for (int i = 0; i < 8; ++i) {
    const int q = n0 + wq*8 + i;
    int* outp = idx_out + (size_t)(b*NN + q)*KK;
    bool need_fix = extract_top20<S>(sv[i], si[i], od[i], outp, lmask);
    if (need_fix) {
      if (lane == 0) { int p = atomicAdd(flag_cnt, 1); flag_list[p & 4095] = b*NN + q; }
    }
  }
}

// ---------------- exact cleanup for flagged queries (rare; ~1 block per query) ------
template<int C>
__global__ void __launch_bounds__(256) knn_fix_kernel(const float* __restrict__ x, int bstride,
                                                      const float* __restrict__ xxb,
                                                      const int* __restrict__ flag_cnt,
                                                      const int* __restrict__ flag_list,
                                                      int* __restrict__ idx_out) {
  __shared__ float redv[4]; __shared__ int redi[4];
  const int tid = threadIdx.x;
  const int wid = tid >> 6, lane = tid & 63;
  const int cnt = flag_cnt[0] < 4096 ? flag_cnt[0] : 4096;
  for (int f = blockIdx.x; f < cnt; f += gridDim.x) {
    const int qn = flag_list[f];
    const int b = qn >> 12, n = qn & (NN-1);
    const float* xb  = x + (size_t)b*bstride;
    const float* xxr = xxb + b*NN;
    float acc[16];
#pragma unroll
    for (int jj = 0; jj < 16; ++jj) acc[jj] = 0.f;
    for (int c = 0; c < C; ++c) {
      const float qc = xb[(size_t)c*NN + n];
      const float* row = xb + (size_t)c*NN + tid;
#pragma unroll
      for (int jj = 0; jj < 16; ++jj) acc[jj] = fmaf(qc, row[256*jj], acc[jj]);
    }
    const float xq = xxr[n];
    float dv[16]; int di[16]; unsigned used = 0;
#pragma unroll
    for (int jj = 0; jj < 16; ++jj) {
      dv[jj] = 2.f*acc[jj] - xq - xxr[tid + 256*jj];
      di[jj] = tid + 256*jj;
    }
    for (int r = 0; r < KK; ++r) {
      float bv = -INFINITY; int bi = 0x7fffffff;
#pragma unroll
      for (int jj = 0; jj < 16; ++jj) {
        bool ok = !((used >> jj) & 1);
        bool bet = ok && (dv[jj] > bv || (dv[jj] == bv && di[jj] < bi));
        bv = bet ? dv[jj] : bv; bi = bet ? di[jj] : bi;
      }
#pragma unroll
      for (int s = 1; s < 64; s <<= 1) {
        float ov = __shfl_xor(bv, s, 64);
        int   oi = __shfl_xor(bi, s, 64);
        if (ov > bv || (ov == bv && oi < bi)) { bv = ov; bi = oi; }
      }
      if (lane == 0) { redv[wid] = bv; redi[wid] = bi; }
      __syncthreads();
#pragma unroll
      for (int w = 0; w < 4; ++w) {
        float ov = redv[w]; int oi = redi[w];
        if (ov > bv || (ov == bv && oi < bi)) { bv = ov; bi = oi; }
      }
      __syncthreads();
      if ((bi & 255) == tid) used |= 1u << (bi >> 8);
      if (tid == 0) idx_out[(size_t)qn*KK + r] = bi;
    }
  }
}

// ---------------- P = W1 . x,  Q = (W2-W1) . x   (both [b][n][o]) ----------------
template<int C, int O>
__global__ void __launch_bounds__(256) pq_kernel(const float* __restrict__ x, int bstride,
                                                 const float* __restrict__ W,
                                                 float* __restrict__ P, float* __restrict__ Q) {
  constexpr int CC = (C < 32) ? C : 32;
  constexpr int NPP = 256 / O;
  constexpr int NITER = 64 / NPP;
  __shared__ float xt[C*64];
  __shared__ float w1t[CC*O];
  __shared__ float wdt[CC*O];
  const int tid = threadIdx.x;
  const int g0 = blockIdx.x*64;
  const int b = g0 >> 12, n0 = g0 & (NN-1);
  for (int i = tid; i < C*64; i += 256) {
    int c = i >> 6, j = i & 63;
    xt[i] = x[(size_t)b*bstride + (size_t)c*NN + (n0 + j)];
  }
  const int o = tid % O;
  const int ns = tid / O;
  float ap[NITER], aq[NITER];
#pragma unroll
  for (int i = 0; i < NITER; ++i) { ap[i] = 0.f; aq[i] = 0.f; }
  for (int cc = 0; cc < C; cc += CC) {
    __syncthreads();
    for (int i = tid; i < CC*O; i += 256) {
      int oo = i % O, c = i / O;
      float w1 = W[oo*(2*C) + cc + c];
      float w2 = W[oo*(2*C) + C + cc + c];
      w1t[c*O + oo] = w1;
      wdt[c*O + oo] = w2 - w1;
    }
    __syncthreads();
#pragma unroll
    for (int np = 0; np < NITER; ++np) {
      const int nl = np*NPP + ns;
#pragma unroll
      for (int c = 0; c < CC; ++c) {
        float xv = xt[(cc + c)*64 + nl];
        ap[np] = fmaf(xv, w1t[c*O + o], ap[np]);
        aq[np] = fmaf(xv, wdt[c*O + o], aq[np]);
      }
    }
  }
#pragma unroll
  for (int np = 0; np < NITER; ++np) {
    const int nl = np*NPP + ns;
    size_t row = (size_t)(g0 + nl)*O + o;
    P[row] = ap[np];
    Q[row] = aq[np];
  }
}

// ---------------- y = P[m]+Q[n]: per-(b,n,o) max/min over k + per-channel partial sums ----
template<int O>
__global__ void __launch_bounds__(256) stats_kernel(const float* __restrict__ P,
                                                    const float* __restrict__ Q,
                                                    const int* __restrict__ idxb,
                                                    float* __restrict__ ymax,
                                                    float* __restrict__ ymin,
                                                    float* __restrict__ parts) {
  constexpr int NPB = 256 / O;
  __shared__ float ls[256], ls2[256];
  const int tid = threadIdx.x;
  const int o = tid % O, ns = tid / O;
  const int g = blockIdx.x*NPB + ns;
  const int b = g >> 12;
  const float qvv = Q[(size_t)g*O + o];
  const int* ip = idxb + (size_t)g*KK;
  const float* Pb = P + (size_t)b*NN*O;
  float s = 0.f, s2 = 0.f, mx = -INFINITY, mn = INFINITY;
#pragma unroll 4
  for (int k = 0; k < KK; ++k) {
    int m = ip[k];
    float yv = Pb[(size_t)m*O + o] + qvv;
    s += yv; s2 = fmaf(yv, yv, s2);
    mx = fmaxf(mx, yv); mn = fminf(mn, yv);
  }
  ymax[(size_t)g*O + o] = mx;
  ymin[(size_t)g*O + o] = mn;
  ls[tid] = s; ls2[tid] = s2;
  __syncthreads();
  if (ns == 0) {
#pragma unroll
    for (int j = 1; j < NPB; ++j) { s += ls[j*O + o]; s2 += ls2[j*O + o]; }
    parts[(size_t)blockIdx.x*2*O + o] = s;
    parts[(size_t)blockIdx.x*2*O + O + o] = s2;
  }
}

// ---------------- per-channel BN affine coefficients (deterministic f64 tree) ----------
template<int O>
__global__ void __launch_bounds__(256) reduce_kernel(const float* __restrict__ parts, int nblocks,
                                                     const float* __restrict__ gg,
                                                     const float* __restrict__ bbp,
                                                     float* __restrict__ chan) {
  __shared__ double sh[512];
  const int o = blockIdx.x, t = threadIdx.x;
  double S = 0.0, S2 = 0.0;
  for (int i = t; i < nblocks; i += 256) {
    S  += (double)parts[(size_t)i*2*O + o];
    S2 += (double)parts[(size_t)i*2*O + O + o];
  }
  sh[t] = S; sh[256+t] = S2;
  __syncthreads();
  for (int s = 128; s > 0; s >>= 1) {
    if (t < s) { sh[t] += sh[t+s]; sh[256+t] += sh[256+t+s]; }
    __syncthreads();
  }
  if (t == 0) {
    const double M = (double)BB*NN*KK;
    double mean = sh[0]/M;
    double var  = sh[256]/M - mean*mean;
    double inv  = 1.0/sqrt(var + 1e-5);
    double A  = (double)gg[o]*inv;
    double Bc = (double)bbp[o] - mean*A;
    chan[2*o]   = (float)A;
    chan[2*o+1] = (float)Bc;
  }
}

// ---------------- out[b][cbase+o][n] = leaky(A*(A>0?ymax:ymin)+Bc), LDS transpose ------
template<int O>
__global__ void __launch_bounds__(256) final_kernel(const float* __restrict__ ymax,
                                                    const float* __restrict__ ymin,
                                                    const float* __restrict__ chan,
                                                    float* __restrict__ out, int cbase) {
  __shared__ float buf[64*(O+1)];
  const int tid = threadIdx.x;
  const int g0 = blockIdx.x*64;
  const int b = g0 >> 12, n0 = g0 & (NN-1);
  for (int i = tid; i < 64*O; i += 256) {
    int o = i % O, nl = i / O;
    size_t r = (size_t)(g0 + nl)*O + o;
    float A = chan[2*o], Bc = chan[2*o+1];
    float v = (A > 0.f) ? ymax[r] : ymin[r];
    float y = fmaf(A, v, Bc);
    buf[nl*(O+1) + o] = (y > 0.f) ? y : 0.2f*y;
  }
  __syncthreads();
  for (int i = tid; i < 64*O; i += 256) {
    int nl = i & 63, o = i >> 6;
    out[(size_t)b*(OUTC*NN) + (size_t)(cbase + o)*NN + (n0 + nl)] = buf[nl*(O+1) + o];
  }
}

extern "C" void kernel_launch(void* const* d_in, const int* in_sizes, int n_in,
                              void* d_out, int out_size, void* d_ws, size_t ws_size,
                              hipStream_t stream) {
  (void)in_sizes; (void)n_in; (void)out_size; (void)ws_size;
  const float* x  = (const float*)d_in[0];
  const float* W0 = (const float*)d_in[1];
  const float* g0 = (const float*)d_in[2];
  const float* b0 = (const float*)d_in[3];
  const float* W1 = (const float*)d_in[4];
  const float* g1 = (const float*)d_in[5];
  const float* b1 = (const float*)d_in[6];
  const float* W2 = (const float*)d_in[7];
  const float* g2 = (const float*)d_in[8];
  const float* b2 = (const float*)d_in[9];
  float* out = (float*)d_out;
  char* ws = (char*)d_ws;

  float* xxb  = (float*)(ws);                       // 64 KB
  int*   idxb = (int*)  (ws + ((size_t)1<<20));     // 1.31 MB
  float* P    = (float*)(ws + ((size_t)4<<20));     // 8 MB
  float* Q    = (float*)(ws + ((size_t)12<<20));    // 8 MB
  float* ymax = (float*)(ws + ((size_t)20<<20));    // 8 MB
  float* ymin = (float*)(ws + ((size_t)28<<20));    // 8 MB
  float* prts = (float*)(ws + ((size_t)36<<20));    // 8 MB
  float* chan = (float*)(ws + ((size_t)44<<20));    // 1 KB
  int*   fcnt = (int*)  (ws + ((size_t)45<<20));    // 3 ints
  int*   flst = (int*)  (ws + ((size_t)45<<20) + 64); // 3*4096 ints
  float* qtb  = (float*)(ws + ((size_t)46<<20));    // 4 MB (transposed q blocks)

  hipMemsetAsync(fcnt, 0, 3*sizeof(int), stream);

  // ---- layer 0: C=3 -> O=64, out channels [0,64) ----
  xx_kernel<3><<<GN/256, 256, 0, stream>>>(x, 3*NN, xxb);
  qt_kernel<3><<<(GN*3)/256, 256, 0, stream>>>(x, 3*NN, qtb);
  knn9_kernel<3><<<GN/32, 256, 0, stream>>>(x, 3*NN, xxb, qtb, idxb, fcnt+0, flst+0*4096);
  knn_fix_kernel<3><<<64, 256, 0, stream>>>(x, 3*NN, xxb, fcnt+0, flst+0*4096, idxb);
  pq_kernel<3,64><<<GN/64, 256, 0, stream>>>(x, 3*NN, W0, P, Q);
  stats_kernel<64><<<GN/4, 256, 0, stream>>>(P, Q, idxb, ymax, ymin, prts);
  reduce_kernel<64><<<64, 256, 0, stream>>>(prts, GN/4, g0, b0, chan);
  final_kernel<64><<<GN/64, 256, 0, stream>>>(ymax, ymin, chan, out, 0);

  // ---- layer 1: C=64 -> O=64, input = out[:,0:64,:], out channels [64,128) ----
  const float* x1 = out;
  xx_kernel<64><<<GN/256, 256, 0, stream>>>(x1, OUTC*NN, xxb);
  qt_kernel<64><<<(GN*64)/256, 256, 0, stream>>>(x1, OUTC*NN, qtb);
  knn9_kernel<64><<<GN/32, 256, 0, stream>>>(x1, OUTC*NN, xxb, qtb, idxb, fcnt+1, flst+1*4096);
  knn_fix_kernel<64><<<64, 256, 0, stream>>>(x1, OUTC*NN, xxb, fcnt+1, flst+1*4096, idxb);
  pq_kernel<64,64><<<GN/64, 256, 0, stream>>>(x1, OUTC*NN, W1, P, Q);
  stats_kernel<64><<<GN/4, 256, 0, stream>>>(P, Q, idxb, ymax, ymin, prts);
  reduce_kernel<64><<<64, 256, 0, stream>>>(prts, GN/4, g1, b1, chan);
  final_kernel<64><<<GN/64, 256, 0, stream>>>(ymax, ymin, chan, out, 64);

  // ---- layer 2: C=64 -> O=128, input = out[:,64:128,:], out channels [128,256) ----
  const float* x2 = out + (size_t)64*NN;
  xx_kernel<64><<<GN/256, 256, 0, stream>>>(x2, OUTC*NN, xxb);
  qt_kernel<64><<<(GN*64)/256, 256, 0, stream>>>(x2, OUTC*NN, qtb);
  knn9_kernel<64><<<GN/32, 256, 0, stream>>>(x2, OUTC*NN, xxb, qtb, idxb, fcnt+2, flst+2*4096);
  knn_fix_kernel<64><<<64, 256, 0, stream>>>(x2, OUTC*NN, xxb, fcnt+2, flst+2*4096, idxb);
  pq_kernel<64,128><<<GN/64, 256, 0, stream>>>(x2, OUTC*NN, W2, P, Q);
  stats_kernel<128><<<GN/2, 256, 0, stream>>>(P, Q, idxb, ymax, ymin, prts);
  reduce_kernel<128><<<128, 256, 0, stream>>>(prts, GN/2, g2, b2, chan);
  final_kernel<128><<<GN/64, 256, 0, stream>>>(ymax, ymin, chan, out, 128);
}

// Round 12
// 809.922 us; speedup vs baseline: 1.3489x; 1.0828x over previous
//
#include <hip/hip_runtime.h>
#include <math.h>

#define NN 4096
#define BB 4
#define KK 20
#define OUTC 256
#define GN (BB*NN)

typedef unsigned int u32;

// async 16B/lane global -> LDS DMA (wave-uniform LDS base, per-lane global src)
__device__ __forceinline__ void gload_lds16(const float* g, float* l) {
  __builtin_amdgcn_global_load_lds((const __attribute__((address_space(1))) u32*)g,
                                   (__attribute__((address_space(3))) u32*)l, 16, 0, 0);
}

// ---------------- xx[b][n] = sum_c x[b][c][n]^2 ----------------
template<int C>
__global__ void __launch_bounds__(256) xx_kernel(const float* __restrict__ x, int bstride,
                                                 float* __restrict__ xxo) {
  int i = blockIdx.x*256 + threadIdx.x;
  int b = i >> 12, n = i & (NN-1);
  const float* xp = x + (size_t)b*bstride + n;
  float s = 0.f;
#pragma unroll
  for (int c = 0; c < C; ++c) { float v = xp[(size_t)c*NN]; s = fmaf(v, v, s); }
  xxo[i] = s;
}

// ---------------- qt[g][c][j] = x[b][c][g*8+j]: contiguous per-wave q blocks --------
template<int C>
__global__ void __launch_bounds__(256) qt_kernel(const float* __restrict__ x, int bstride,
                                                 float* __restrict__ qt) {
  int o = blockIdx.x*256 + threadIdx.x;          // o < GN*C
  int g = o / (C*8); int r = o - g*(C*8); int c = r >> 3; int j = r & 7;
  int gq = g*8 + j; int b = gq >> 12; int n = gq & (NN-1);
  qt[o] = x[(size_t)b*bstride + (size_t)c*NN + n];
}

__device__ __forceinline__ unsigned ord_u32(float v) {
  unsigned b = __float_as_uint(v);
  return (b & 0x80000000u) ? ~b : (b | 0x80000000u);
}

// Exact top-KK extraction from 64 lanes x S register slots via ballot bit-bisect.
// Order semantics: (value desc, idx asc) == jax.lax.top_k. Emits the index SET
// (downstream sum/max over k is order-invariant). Returns true iff this query
// needs the exact-cleanup pass: some lane discarded a value od that could have
// belonged to the true top-20 (ord(od) >= T, conservative on exact ties).
template<int S>
__device__ __forceinline__ bool extract_top20(const float (&sv)[S], const int (&si)[S],
                                              float od, int* __restrict__ outp,
                                              unsigned long long lmask) {
  unsigned u[S];
#pragma unroll
  for (int k = 0; k < S; ++k) u[k] = ord_u32(sv[k]);
  unsigned T = 0u;
#pragma unroll 1
  for (int bit = 31; bit >= 0; --bit) {
    unsigned Tp = T | (1u << bit);
    int c = 0;
#pragma unroll
    for (int k = 0; k < S; ++k) c += __popcll(__ballot(u[k] >= Tp));
    if (c >= KK) T = Tp;
  }
  int cgt = 0;
#pragma unroll
  for (int k = 0; k < S; ++k) cgt += __popcll(__ballot(u[k] > T));
  const int r = KK - cgt;
  int A = 0;
#pragma unroll 1
  for (int bit = 11; bit >= 0; --bit) {
    int Ap = A | (1 << bit);
    int c = 0;
#pragma unroll
    for (int k = 0; k < S; ++k) c += __popcll(__ballot(u[k] == T && si[k] < Ap));
    if (c < r) A = Ap;
  }
  int base = 0;
#pragma unroll
  for (int k = 0; k < S; ++k) {
    bool kp = (u[k] > T) || (u[k] == T && si[k] <= A);
    unsigned long long mk = __ballot(kp);
    int pos = base + __popcll(mk & lmask);
    if (kp) outp[pos] = si[k];
    base += __popcll(mk);
  }
  return __ballot(ord_u32(od) >= T) != 0ull;
}

// ---------------- KNN: gload_lds pipeline, 8 q/wave, M=4/lane, top-4 + od ------
// R11 lesson: M=8 needed acc[8][8]=64 regs -> ~160 live -> 52MB scratch spill at
// the 128-VGPR allocation. M=4 (256-cand tiles, 16 tiles) halves acc to 32 and
// xq moves to LDS-read-at-distance-time: ~104 live + temps fits 128, no spill.
// Per phase: ISSUE async DMA (1KB = one channel row per segment, 2 seg/wave) for
// phase p+1 into cand[buf^1], compute phase p (8c x {1 ds_read_b128 + 32 FMA}),
// one __syncthreads() (vmcnt(0)+barrier drains DMA). q via transposed qt array
// (wave-uniform 32B -> s_load). od invariant (proven R8): od = max over all
// discards = max(min(d, old sv[S-1])). Distance fma chain order (c ascending
// per tile) identical to the validated R1..R11 kernels.
template<int C>
__global__ void __launch_bounds__(256)
__attribute__((amdgpu_waves_per_eu(2, 2)))
knn10_kernel(const float* __restrict__ x, int bstride,
             const float* __restrict__ xxb,
             const float* __restrict__ qt,
             int* __restrict__ idx_out,
             int* __restrict__ flag_cnt,
             int* __restrict__ flag_list) {
  constexpr int CC = (C < 8) ? C : 8;
  constexpr int NCH = C / CC;              // 1 for C=3, 8 for C=64
  constexpr int NT = NN/256;               // 16 candidate tiles
  constexpr int P = NT * NCH;              // pipeline phases
  constexpr int NSEG = CC;                 // 1KB segments per chunk (1 channel row)
  constexpr int NPW = (NSEG + 3)/4;        // segments per wave
  constexpr int S = 4;
  __shared__ float cand[2][CC][256];
  __shared__ float xq_lds[32];
  const int tid = threadIdx.x;
  const int wq = tid >> 6, lane = tid & 63;
  const unsigned long long lmask = (1ull << lane) - 1ull;
  const int qb = blockIdx.x;
  const int b = qb >> 7, n0 = (qb & 127) << 5;
  const float* xb  = x + (size_t)b*bstride;
  const float* xxr = xxb + b*NN;
  // wave-uniform transposed-q pointer (readfirstlane -> SGPR -> s_load)
  const int ug = __builtin_amdgcn_readfirstlane(((b << 12) + n0 + wq*8) >> 3);
  const float* qtp = qt + (size_t)ug*C*8;

  if (tid < 32) xq_lds[tid] = xxr[n0 + tid];

  // ---- prologue: stage phase 0 into cand[0] ----
#pragma unroll
  for (int i = 0; i < NPW; ++i) {
    int seg = wq + i*4;                    // wave-uniform
    if (NSEG == 4*NPW || seg < NSEG) {
      gload_lds16(xb + (size_t)seg*NN + lane*4, &cand[0][seg][0]);
    }
  }
  __syncthreads();                         // drains DMA + xq_lds writes

  float sv[8][S]; int si[8][S]; float od[8];
#pragma unroll
  for (int i = 0; i < 8; ++i) {
    od[i] = -INFINITY;
#pragma unroll
    for (int k = 0; k < S; ++k) { sv[i][k] = -INFINITY; si[i][k] = 0x7fffffff; }
  }

  float acc[8][4];

#pragma unroll 1
  for (int p = 0; p < P; ++p) {
    const int tp = p / NCH, cp = p - tp*NCH;
    const int buf = p & 1;
    const int mt0 = tp*256;
    const int cbase = cp*CC;

    // ---- ISSUE async DMA for phase p+1 (zero VGPR cost; lands by next barrier) ----
    const int pn = p + 1;
    if (pn < P) {
      const int tpn = pn / NCH, cpn = pn - tpn*NCH;
      const int mt0n = tpn*256, cbn = cpn*CC;
#pragma unroll
      for (int i = 0; i < NPW; ++i) {
        int seg = wq + i*4;
        if (NSEG == 4*NPW || seg < NSEG) {
          gload_lds16(xb + (size_t)(cbn + seg)*NN + mt0n + lane*4,
                      &cand[buf ^ 1][seg][0]);
        }
      }
    }

    // ---- compute phase p ----
    if (cp == 0) {
#pragma unroll
      for (int i = 0; i < 8; ++i)
#pragma unroll
        for (int j = 0; j < 4; ++j) acc[i][j] = 0.f;
    }
#pragma unroll
    for (int c = 0; c < CC; ++c) {
      const float* qc = qtp + (size_t)(cbase + c)*8;   // uniform 32B -> s_load
      float qq[8];
#pragma unroll
      for (int i = 0; i < 8; ++i) qq[i] = qc[i];
      float4 ca = *reinterpret_cast<const float4*>(&cand[buf][c][lane*4]);
      float mm[4] = {ca.x, ca.y, ca.z, ca.w};
#pragma unroll
      for (int i = 0; i < 8; ++i)
#pragma unroll
        for (int j = 0; j < 4; ++j) acc[i][j] = fmaf(qq[i], mm[j], acc[i][j]);
    }

    if (cp == NCH - 1) {
      // distances + selection for tile tp (xm straight from global, L2-hot)
      float4 xma = *reinterpret_cast<const float4*>(&xxr[mt0 + lane*4]);
      float xmv[4] = {xma.x, xma.y, xma.z, xma.w};
#pragma unroll
      for (int i = 0; i < 8; ++i) {
        const float xqi = xq_lds[wq*8 + i];            // broadcast LDS read
#pragma unroll
        for (int j = 0; j < 4; ++j) {
          const float d = 2.f*acc[i][j] - xqi - xmv[j];
          const int mi = mt0 + lane*4 + j;
          od[i] = fmaxf(od[i], fminf(d, sv[i][3]));    // all discards tracked
          bool c0 = d > sv[i][0], c1 = d > sv[i][1], c2 = d > sv[i][2], c3 = d > sv[i][3];
          sv[i][3] = c2 ? sv[i][2] : (c3 ? d : sv[i][3]);  si[i][3] = c2 ? si[i][2] : (c3 ? mi : si[i][3]);
          sv[i][2] = c1 ? sv[i][1] : (c2 ? d : sv[i][2]);  si[i][2] = c1 ? si[i][1] : (c2 ? mi : si[i][2]);
          sv[i][1] = c0 ? sv[i][0] : (c1 ? d : sv[i][1]);  si[i][1] = c0 ? si[i][0] : (c1 ? mi : si[i][1]);
          sv[i][0] = c0 ? d : sv[i][0];                    si[i][0] = c0 ? mi : si[i][0];
        }
      }
    }

    __syncthreads();   // drains phase p+1 DMA for every wave; guards buffer reuse
  }

  // extraction: fully unrolled over the 8 queries (static register indexing)
#pragma unroll
  for (int i = 0; i < 8; ++i) {
    const int q = n0 + wq*8 + i;
    int* outp = idx_out + (size_t)(b*NN + q)*KK;
    bool need_fix = extract_top20<S>(sv[i], si[i], od[i], outp, lmask);
    if (need_fix) {
      if (lane == 0) { int p = atomicAdd(flag_cnt, 1); flag_list[p & 4095] = b*NN + q; }
    }
  }
}

// ---------------- exact cleanup for flagged queries (rare; ~1 block per query) ------
template<int C>
__global__ void __launch_bounds__(256) knn_fix_kernel(const float* __restrict__ x, int bstride,
                                                      const float* __restrict__ xxb,
                                                      const int* __restrict__ flag_cnt,
                                                      const int* __restrict__ flag_list,
                                                      int* __restrict__ idx_out) {
  __shared__ float redv[4]; __shared__ int redi[4];
  const int tid = threadIdx.x;
  const int wid = tid >> 6, lane = tid & 63;
  const int cnt = flag_cnt[0] < 4096 ? flag_cnt[0] : 4096;
  for (int f = blockIdx.x; f < cnt; f += gridDim.x) {
    const int qn = flag_list[f];
    const int b = qn >> 12, n = qn & (NN-1);
    const float* xb  = x + (size_t)b*bstride;
    const float* xxr = xxb + b*NN;
    float acc[16];
#pragma unroll
    for (int jj = 0; jj < 16; ++jj) acc[jj] = 0.f;
    for (int c = 0; c < C; ++c) {
      const float qc = xb[(size_t)c*NN + n];
      const float* row = xb + (size_t)c*NN + tid;
#pragma unroll
      for (int jj = 0; jj < 16; ++jj) acc[jj] = fmaf(qc, row[256*jj], acc[jj]);
    }
    const float xq = xxr[n];
    float dv[16]; int di[16]; unsigned used = 0;
#pragma unroll
    for (int jj = 0; jj < 16; ++jj) {
      dv[jj] = 2.f*acc[jj] - xq - xxr[tid + 256*jj];
      di[jj] = tid + 256*jj;
    }
    for (int r = 0; r < KK; ++r) {
      float bv = -INFINITY; int bi = 0x7fffffff;
#pragma unroll
      for (int jj = 0; jj < 16; ++jj) {
        bool ok = !((used >> jj) & 1);
        bool bet = ok && (dv[jj] > bv || (dv[jj] == bv && di[jj] < bi));
        bv = bet ? dv[jj] : bv; bi = bet ? di[jj] : bi;
      }
#pragma unroll
      for (int s = 1; s < 64; s <<= 1) {
        float ov = __shfl_xor(bv, s, 64);
        int   oi = __shfl_xor(bi, s, 64);
        if (ov > bv || (ov == bv && oi < bi)) { bv = ov; bi = oi; }
      }
      if (lane == 0) { redv[wid] = bv; redi[wid] = bi; }
      __syncthreads();
#pragma unroll
      for (int w = 0; w < 4; ++w) {
        float ov = redv[w]; int oi = redi[w];
        if (ov > bv || (ov == bv && oi < bi)) { bv = ov; bi = oi; }
      }
      __syncthreads();
      if ((bi & 255) == tid) used |= 1u << (bi >> 8);
      if (tid == 0) idx_out[(size_t)qn*KK + r] = bi;
    }
  }
}

// ---------------- P = W1 . x,  Q = (W2-W1) . x   (both [b][n][o]) ----------------
template<int C, int O>
__global__ void __launch_bounds__(256) pq_kernel(const float* __restrict__ x, int bstride,
                                                 const float* __restrict__ W,
                                                 float* __restrict__ P, float* __restrict__ Q) {
  constexpr int CC = (C < 32) ? C : 32;
  constexpr int NPP = 256 / O;
  constexpr int NITER = 64 / NPP;
  __shared__ float xt[C*64];
  __shared__ float w1t[CC*O];
  __shared__ float wdt[CC*O];
  const int tid = threadIdx.x;
  const int g0 = blockIdx.x*64;
  const int b = g0 >> 12, n0 = g0 & (NN-1);
  for (int i = tid; i < C*64; i += 256) {
    int c = i >> 6, j = i & 63;
    xt[i] = x[(size_t)b*bstride + (size_t)c*NN + (n0 + j)];
  }
  const int o = tid % O;
  const int ns = tid / O;
  float ap[NITER], aq[NITER];
#pragma unroll
  for (int i = 0; i < NITER; ++i) { ap[i] = 0.f; aq[i] = 0.f; }
  for (int cc = 0; cc < C; cc += CC) {
    __syncthreads();
    for (int i = tid; i < CC*O; i += 256) {
      int oo = i % O, c = i / O;
      float w1 = W[oo*(2*C) + cc + c];
      float w2 = W[oo*(2*C) + C + cc + c];
      w1t[c*O + oo] = w1;
      wdt[c*O + oo] = w2 - w1;
    }
    __syncthreads();
#pragma unroll
    for (int np = 0; np < NITER; ++np) {
      const int nl = np*NPP + ns;
#pragma unroll
      for (int c = 0; c < CC; ++c) {
        float xv = xt[(cc + c)*64 + nl];
        ap[np] = fmaf(xv, w1t[c*O + o], ap[np]);
        aq[np] = fmaf(xv, wdt[c*O + o], aq[np]);
      }
    }
  }
#pragma unroll
  for (int np = 0; np < NITER; ++np) {
    const int nl = np*NPP + ns;
    size_t row = (size_t)(g0 + nl)*O + o;
    P[row] = ap[np];
    Q[row] = aq[np];
  }
}

// ---------------- y = P[m]+Q[n]: per-(b,n,o) max/min over k + per-channel partial sums ----
template<int O>
__global__ void __launch_bounds__(256) stats_kernel(const float* __restrict__ P,
                                                    const float* __restrict__ Q,
                                                    const int* __restrict__ idxb,
                                                    float* __restrict__ ymax,
                                                    float* __restrict__ ymin,
                                                    float* __restrict__ parts) {
  constexpr int NPB = 256 / O;
  __shared__ float ls[256], ls2[256];
  const int tid = threadIdx.x;
  const int o = tid % O, ns = tid / O;
  const int g = blockIdx.x*NPB + ns;
  const int b = g >> 12;
  const float qvv = Q[(size_t)g*O + o];
  const int* ip = idxb + (size_t)g*KK;
  const float* Pb = P + (size_t)b*NN*O;
  float s = 0.f, s2 = 0.f, mx = -INFINITY, mn = INFINITY;
#pragma unroll 4
  for (int k = 0; k < KK; ++k) {
    int m = ip[k];
    float yv = Pb[(size_t)m*O + o] + qvv;
    s += yv; s2 = fmaf(yv, yv, s2);
    mx = fmaxf(mx, yv); mn = fminf(mn, yv);
  }
  ymax[(size_t)g*O + o] = mx;
  ymin[(size_t)g*O + o] = mn;
  ls[tid] = s; ls2[tid] = s2;
  __syncthreads();
  if (ns == 0) {
#pragma unroll
    for (int j = 1; j < NPB; ++j) { s += ls[j*O + o]; s2 += ls2[j*O + o]; }
    parts[(size_t)blockIdx.x*2*O + o] = s;
    parts[(size_t)blockIdx.x*2*O + O + o] = s2;
  }
}

// ---------------- per-channel BN affine coefficients (deterministic f64 tree) ----------
template<int O>
__global__ void __launch_bounds__(256) reduce_kernel(const float* __restrict__ parts, int nblocks,
                                                     const float* __restrict__ gg,
                                                     const float* __restrict__ bbp,
                                                     float* __restrict__ chan) {
  __shared__ double sh[512];
  const int o = blockIdx.x, t = threadIdx.x;
  double S = 0.0, S2 = 0.0;
  for (int i = t; i < nblocks; i += 256) {
    S  += (double)parts[(size_t)i*2*O + o];
    S2 += (double)parts[(size_t)i*2*O + O + o];
  }
  sh[t] = S; sh[256+t] = S2;
  __syncthreads();
  for (int s = 128; s > 0; s >>= 1) {
    if (t < s) { sh[t] += sh[t+s]; sh[256+t] += sh[256+t+s]; }
    __syncthreads();
  }
  if (t == 0) {
    const double M = (double)BB*NN*KK;
    double mean = sh[0]/M;
    double var  = sh[256]/M - mean*mean;
    double inv  = 1.0/sqrt(var + 1e-5);
    double A  = (double)gg[o]*inv;
    double Bc = (double)bbp[o] - mean*A;
    chan[2*o]   = (float)A;
    chan[2*o+1] = (float)Bc;
  }
}

// ---------------- out[b][cbase+o][n] = leaky(A*(A>0?ymax:ymin)+Bc), LDS transpose ------
template<int O>
__global__ void __launch_bounds__(256) final_kernel(const float* __restrict__ ymax,
                                                    const float* __restrict__ ymin,
                                                    const float* __restrict__ chan,
                                                    float* __restrict__ out, int cbase) {
  __shared__ float buf[64*(O+1)];
  const int tid = threadIdx.x;
  const int g0 = blockIdx.x*64;
  const int b = g0 >> 12, n0 = g0 & (NN-1);
  for (int i = tid; i < 64*O; i += 256) {
    int o = i % O, nl = i / O;
    size_t r = (size_t)(g0 + nl)*O + o;
    float A = chan[2*o], Bc = chan[2*o+1];
    float v = (A > 0.f) ? ymax[r] : ymin[r];
    float y = fmaf(A, v, Bc);
    buf[nl*(O+1) + o] = (y > 0.f) ? y : 0.2f*y;
  }
  __syncthreads();
  for (int i = tid; i < 64*O; i += 256) {
    int nl = i & 63, o = i >> 6;
    out[(size_t)b*(OUTC*NN) + (size_t)(cbase + o)*NN + (n0 + nl)] = buf[nl*(O+1) + o];
  }
}

extern "C" void kernel_launch(void* const* d_in, const int* in_sizes, int n_in,
                              void* d_out, int out_size, void* d_ws, size_t ws_size,
                              hipStream_t stream) {
  (void)in_sizes; (void)n_in; (void)out_size; (void)ws_size;
  const float* x  = (const float*)d_in[0];
  const float* W0 = (const float*)d_in[1];
  const float* g0 = (const float*)d_in[2];
  const float* b0 = (const float*)d_in[3];
  const float* W1 = (const float*)d_in[4];
  const float* g1 = (const float*)d_in[5];
  const float* b1 = (const float*)d_in[6];
  const float* W2 = (const float*)d_in[7];
  const float* g2 = (const float*)d_in[8];
  const float* b2 = (const float*)d_in[9];
  float* out = (float*)d_out;
  char* ws = (char*)d_ws;

  float* xxb  = (float*)(ws);                       // 64 KB
  int*   idxb = (int*)  (ws + ((size_t)1<<20));     // 1.31 MB
  float* P    = (float*)(ws + ((size_t)4<<20));     // 8 MB
  float* Q    = (float*)(ws + ((size_t)12<<20));    // 8 MB
  float* ymax = (float*)(ws + ((size_t)20<<20));    // 8 MB
  float* ymin = (float*)(ws + ((size_t)28<<20));    // 8 MB
  float* prts = (float*)(ws + ((size_t)36<<20));    // 8 MB
  float* chan = (float*)(ws + ((size_t)44<<20));    // 1 KB
  int*   fcnt = (int*)  (ws + ((size_t)45<<20));    // 3 ints
  int*   flst = (int*)  (ws + ((size_t)45<<20) + 64); // 3*4096 ints
  float* qtb  = (float*)(ws + ((size_t)46<<20));    // 4 MB (transposed q blocks)

  hipMemsetAsync(fcnt, 0, 3*sizeof(int), stream);

  // ---- layer 0: C=3 -> O=64, out channels [0,64) ----
  xx_kernel<3><<<GN/256, 256, 0, stream>>>(x, 3*NN, xxb);
  qt_kernel<3><<<(GN*3)/256, 256, 0, stream>>>(x, 3*NN, qtb);
  knn10_kernel<3><<<GN/32, 256, 0, stream>>>(x, 3*NN, xxb, qtb, idxb, fcnt+0, flst+0*4096);
  knn_fix_kernel<3><<<64, 256, 0, stream>>>(x, 3*NN, xxb, fcnt+0, flst+0*4096, idxb);
  pq_kernel<3,64><<<GN/64, 256, 0, stream>>>(x, 3*NN, W0, P, Q);
  stats_kernel<64><<<GN/4, 256, 0, stream>>>(P, Q, idxb, ymax, ymin, prts);
  reduce_kernel<64><<<64, 256, 0, stream>>>(prts, GN/4, g0, b0, chan);
  final_kernel<64><<<GN/64, 256, 0, stream>>>(ymax, ymin, chan, out, 0);

  // ---- layer 1: C=64 -> O=64, input = out[:,0:64,:], out channels [64,128) ----
  const float* x1 = out;
  xx_kernel<64><<<GN/256, 256, 0, stream>>>(x1, OUTC*NN, xxb);
  qt_kernel<64><<<(GN*64)/256, 256, 0, stream>>>(x1, OUTC*NN, qtb);
  knn10_kernel<64><<<GN/32, 256, 0, stream>>>(x1, OUTC*NN, xxb, qtb, idxb, fcnt+1, flst+1*4096);
  knn_fix_kernel<64><<<64, 256, 0, stream>>>(x1, OUTC*NN, xxb, fcnt+1, flst+1*4096, idxb);
  pq_kernel<64,64><<<GN/64, 256, 0, stream>>>(x1, OUTC*NN, W1, P, Q);
  stats_kernel<64><<<GN/4, 256, 0, stream>>>(P, Q, idxb, ymax, ymin, prts);
  reduce_kernel<64><<<64, 256, 0, stream>>>(prts, GN/4, g1, b1, chan);
  final_kernel<64><<<GN/64, 256, 0, stream>>>(ymax, ymin, chan, out, 64);

  // ---- layer 2: C=64 -> O=128, input = out[:,64:128,:], out channels [128,256) ----
  const float* x2 = out + (size_t)64*NN;
  xx_kernel<64><<<GN/256, 256, 0, stream>>>(x2, OUTC*NN, xxb);
  qt_kernel<64><<<(GN*64)/256, 256, 0, stream>>>(x2, OUTC*NN, qtb);
  knn10_kernel<64><<<GN/32, 256, 0, stream>>>(x2, OUTC*NN, xxb, qtb, idxb, fcnt+2, flst+2*4096);
  knn_fix_kernel<64><<<64, 256, 0, stream>>>(x2, OUTC*NN, xxb, fcnt+2, flst+2*4096, idxb);
  pq_kernel<64,128><<<GN/64, 256, 0, stream>>>(x2, OUTC*NN, W2, P, Q);
  stats_kernel<128><<<GN/2, 256, 0, stream>>>(P, Q, idxb, ymax, ymin, prts);
  reduce_kernel<128><<<128, 256, 0, stream>>>(prts, GN/2, g2, b2, chan);
  final_kernel<128><<<GN/64, 256, 0, stream>>>(ymax, ymin, chan, out, 128);
}